// Round 4
// baseline (945.973 us; speedup 1.0000x reference)
//
#include <hip/hip_runtime.h>
#include <stdint.h>

#define D 512
#define NW 8
#define BATCH 8192
#define XROW 8704          // 17*D
#define BM 128
#define BK 32
#define KT 16              // 512 / BK
#define MAT 262144         // 512*512

typedef __attribute__((ext_vector_type(8))) short bf16x8;
typedef __attribute__((ext_vector_type(4))) float f32x4;

struct Params {
  const float* x;
  const float* bq; const float* bkc;
  const float* bkp; const float* bkn;
  const float* bfp; const float* bfn;
  const float* bfc;
  const unsigned short* Wb;   // 35 bf16 512x512 matrices
  const unsigned short* xb;   // bf16 copy of x [B][17*D]
  unsigned short* qw;         // q  bf16 [B][D]
  unsigned short* kcw;        // kc bf16 [B][D]
  float* ap; float* an;       // [B][8]
  unsigned short* xcn;        // normalized center bf16 [B][D]
  float* out;
};

__device__ __forceinline__ unsigned short f2bf(float f) {
  union { float f; unsigned u; } v; v.f = f;
  unsigned u = v.u + 0x7FFFu + ((v.u >> 16) & 1u);   // RNE
  return (unsigned short)(u >> 16);
}
__device__ __forceinline__ float bf2f(unsigned short h) {
  union { unsigned u; float f; } v; v.u = ((unsigned)h) << 16;
  return v.f;
}

// K0: convert weights AND x fp32 -> bf16 into ws.
__global__ void convert_all(const float* x, const float* Wq, const float* Wkc,
                            const float* Wkp, const float* Wkn, const float* Wfp,
                            const float* Wfn, const float* Wfc,
                            unsigned short* Wb, unsigned short* xb) {
  const int totW = 35 * MAT;
  const int total4 = (totW + BATCH * XROW) / 4;
  for (int i4 = blockIdx.x * blockDim.x + threadIdx.x; i4 < total4;
       i4 += gridDim.x * blockDim.x) {
    int idx = i4 * 4;
    const float* src;
    unsigned short* dst;
    if (idx < totW) {
      int m = idx >> 18;
      int e = idx & (MAT - 1);
      if (m == 0)       src = Wq + e;
      else if (m == 1)  src = Wkc + e;
      else if (m < 10)  src = Wkp + (size_t)(m - 2) * MAT + e;
      else if (m < 18)  src = Wkn + (size_t)(m - 10) * MAT + e;
      else if (m < 26)  src = Wfp + (size_t)(m - 18) * MAT + e;
      else if (m < 34)  src = Wfn + (size_t)(m - 26) * MAT + e;
      else              src = Wfc + e;
      dst = Wb + idx;
    } else {
      int e = idx - totW;
      src = x + e;
      dst = xb + e;
    }
    float4 v = *reinterpret_cast<const float4*>(src);
    ushort4 o;
    o.x = f2bf(v.x); o.y = f2bf(v.y); o.z = f2bf(v.z); o.w = f2bf(v.w);
    *reinterpret_cast<ushort4*>(dst) = o;
  }
}

#define GLOAD(SRC, DST) __builtin_amdgcn_global_load_lds( \
    (const __attribute__((address_space(1))) unsigned*)(SRC), \
    (__attribute__((address_space(3))) unsigned*)(DST), 16, 0, 0)

// Pipelined batched GEMM, BM=128 x BN=512(full) x BK=32, 512 threads (8 waves,
// 2Mx4N, wave-tile 64x128). A and B both staged bf16 via global_load_lds with
// rule-21 pre-swizzled source (involution o^((o>>3)&0x70) on 64-B rows).
// T3/T4 2-phase: double-buffered LDS, counted vmcnt(5) (never 0 mid-loop),
// raw s_barrier (no compiler drain), sched_barrier fences, T5 setprio.
// Epilogues fused per unit (same as round-3 kernel, which passed).
__launch_bounds__(512)
__global__ void gemm_mega(Params p, int launch_id) {
  __shared__ unsigned short lds2[2][20480];  // 2 x (A 8KB @0 + B 32KB @4096e) = 80 KiB

  const int nchunk = gridDim.x >> 3;         // gridDim.x % 8 == 0 for all launches
  const int swz  = (blockIdx.x & 7) * nchunk + (blockIdx.x >> 3);
  const int unit = swz >> 6;
  const int mb   = swz & 63;
  const int t    = threadIdx.x;
  const int lane = t & 63;
  const int wave = t >> 6;
  const int wm   = wave >> 2;   // 0..1  (64 rows each)
  const int wn   = wave & 3;    // 0..3  (128 cols each)

  const unsigned short* Aab = p.xb;
  int lda = XROW;
  int aofs = 0;
  const unsigned short* Wm = p.Wb;
  const float* bias = p.bq;
  int epi = 0;
  int outofs = 0;
  float* dotdst = nullptr;
  int wofs = 0;

  if (launch_id == 0) {
    if (unit == 0)      { aofs = 8 * D; Wm = p.Wb;            bias = p.bq;  epi = 0; }
    else if (unit == 1) { aofs = 8 * D; Wm = p.Wb + MAT;      bias = p.bkc; epi = 1; }
    else if (unit < 10) { int w = unit - 2;  aofs = w * D;
                          Wm = p.Wb + (size_t)(18 + w) * MAT; bias = p.bfp + w * D;
                          epi = 2; outofs = w * D; }
    else                { int w = unit - 10; aofs = (9 + w) * D;
                          Wm = p.Wb + (size_t)(26 + w) * MAT; bias = p.bfn + w * D;
                          epi = 2; outofs = (9 + w) * D; }
  } else if (launch_id == 1) {
    if (unit < 8) { int w = unit;     aofs = w * D;
                    Wm = p.Wb + (size_t)(2 + w) * MAT;  bias = p.bkp + w * D;
                    epi = 3; dotdst = p.ap; wofs = w; }
    else          { int w = unit - 8; aofs = (9 + w) * D;
                    Wm = p.Wb + (size_t)(10 + w) * MAT; bias = p.bkn + w * D;
                    epi = 3; dotdst = p.an; wofs = w; }
  } else {
    Aab = p.xcn; lda = D; aofs = 0;
    Wm = p.Wb + (size_t)34 * MAT; bias = p.bfc; epi = 4; outofs = 8 * D;
  }

  const int row0 = mb * BM;

  f32x4 acc[4][8];
#pragma unroll
  for (int m = 0; m < 4; ++m)
#pragma unroll
    for (int n = 0; n < 8; ++n)
      acc[m][n] = (f32x4){0.f, 0.f, 0.f, 0.f};

  // Per-thread pre-swizzled global sources (kt=0); kt advances by +32 elems.
  const unsigned short* aST;
  {
    int o = t * 16; int Ls = o ^ ((o >> 3) & 0x70);
    aST = Aab + (size_t)(row0 + (Ls >> 6)) * lda + aofs + ((Ls & 63) >> 1);
  }
  const unsigned short* bSTa[4];
#pragma unroll
  for (int j = 0; j < 4; ++j) {
    int o = t * 16 + j * 8192; int Ls = o ^ ((o >> 3) & 0x70);
    bSTa[j] = Wm + (size_t)(Ls >> 6) * D + ((Ls & 63) >> 1);
  }

#define STAGE(S, KE) do { \
    GLOAD(aST + (KE), &lds2[S][0] + wave * 512); \
    _Pragma("unroll") \
    for (int j = 0; j < 4; ++j) \
      GLOAD(bSTa[j] + (KE), &lds2[S][4096 + j * 4096] + wave * 512); \
  } while (0)

#define CSTEP(S) do { \
    bf16x8 af[4], bfr[8]; \
    const int kb = (lane >> 4) * 16; \
    _Pragma("unroll") for (int m = 0; m < 4; ++m) { \
      int L = ((wm * 64 + m * 16 + (lane & 15)) << 6) + kb; \
      af[m] = *reinterpret_cast<const bf16x8*>((const char*)&lds2[S][0] + (L ^ ((L >> 3) & 0x70))); } \
    _Pragma("unroll") for (int n = 0; n < 8; ++n) { \
      int L = ((wn * 128 + n * 16 + (lane & 15)) << 6) + kb; \
      bfr[n] = *reinterpret_cast<const bf16x8*>((const char*)&lds2[S][4096] + (L ^ ((L >> 3) & 0x70))); } \
    asm volatile("s_waitcnt lgkmcnt(0)" ::: "memory"); \
    __builtin_amdgcn_sched_barrier(0); \
    __builtin_amdgcn_s_setprio(1); \
    _Pragma("unroll") for (int m = 0; m < 4; ++m) \
      _Pragma("unroll") for (int n = 0; n < 8; ++n) \
        acc[m][n] = __builtin_amdgcn_mfma_f32_16x16x32_bf16(af[m], bfr[n], acc[m][n], 0, 0, 0); \
    __builtin_amdgcn_s_setprio(0); \
  } while (0)

  STAGE(0, 0);
  for (int kt = 0; kt < KT - 1; ++kt) {
    const int cur = kt & 1;
    STAGE(cur ^ 1, (kt + 1) * 32);
    __builtin_amdgcn_sched_barrier(0);
    asm volatile("s_waitcnt vmcnt(5)" ::: "memory");   // cur buffer landed; next 5 in flight
    __builtin_amdgcn_sched_barrier(0);
    __builtin_amdgcn_s_barrier();
    __builtin_amdgcn_sched_barrier(0);
    CSTEP(cur);
    __builtin_amdgcn_sched_barrier(0);
    __builtin_amdgcn_s_barrier();                      // readers done before buf reused
  }
  __builtin_amdgcn_sched_barrier(0);
  asm volatile("s_waitcnt vmcnt(0)" ::: "memory");     // final drain (once)
  __builtin_amdgcn_sched_barrier(0);
  __builtin_amdgcn_s_barrier();
  __builtin_amdgcn_sched_barrier(0);
  CSTEP(1);                                            // kt=15 -> buf 1
  __builtin_amdgcn_sched_barrier(0);
  __builtin_amdgcn_s_barrier();

  // ---- epilogue (lds2[0] dead; overlay reduction buffer) ----
  float* red = (float*)(&lds2[0][0]);
  const int rj = (lane >> 4) * 4;
  const int cl = lane & 15;
  float bv[8];
#pragma unroll
  for (int n = 0; n < 8; ++n) bv[n] = bias[wn * 128 + n * 16 + cl];
#pragma unroll
  for (int m = 0; m < 4; ++m)
#pragma unroll
    for (int n = 0; n < 8; ++n)
#pragma unroll
      for (int j = 0; j < 4; ++j)
        acc[m][n][j] += bv[n];

  if (epi <= 1) {
    unsigned short* dst = (epi == 0) ? p.qw : p.kcw;
#pragma unroll
    for (int m = 0; m < 4; ++m)
#pragma unroll
      for (int j = 0; j < 4; ++j) {
        int r = wm * 64 + m * 16 + rj + j;
#pragma unroll
        for (int n = 0; n < 8; ++n) {
          int col = wn * 128 + n * 16 + cl;
          dst[(size_t)(row0 + r) * D + col] = f2bf(acc[m][n][j]);
        }
      }
  } else if (epi == 3) {
    if (t < BM) red[t] = 0.f;
    __syncthreads();
#pragma unroll
    for (int m = 0; m < 4; ++m)
#pragma unroll
      for (int j = 0; j < 4; ++j) {
        int r = wm * 64 + m * 16 + rj + j;
        float s = 0.f;
#pragma unroll
        for (int n = 0; n < 8; ++n) {
          int col = wn * 128 + n * 16 + cl;
          s += acc[m][n][j] * bf2f(p.qw[(size_t)(row0 + r) * D + col]);
        }
        s += __shfl_xor(s, 1); s += __shfl_xor(s, 2);
        s += __shfl_xor(s, 4); s += __shfl_xor(s, 8);
        if (cl == 0) atomicAdd(&red[r], s);
      }
    __syncthreads();
    if (t < BM) dotdst[(size_t)(row0 + t) * NW + wofs] = red[t];
  } else {
    if (epi == 4) {
#pragma unroll
      for (int m = 0; m < 4; ++m)
#pragma unroll
        for (int j = 0; j < 4; ++j) {
          int r = wm * 64 + m * 16 + rj + j;
#pragma unroll
          for (int n = 0; n < 8; ++n) {
            int col = wn * 128 + n * 16 + cl;
            acc[m][n][j] += p.x[(size_t)(row0 + r) * XROW + 8 * D + col];
          }
        }
    }
    if (t < BM) red[t] = 0.f;
    __syncthreads();
#pragma unroll
    for (int m = 0; m < 4; ++m)
#pragma unroll
      for (int j = 0; j < 4; ++j) {
        int r = wm * 64 + m * 16 + rj + j;
        float s = 0.f;
#pragma unroll
        for (int n = 0; n < 8; ++n) s += acc[m][n][j] * acc[m][n][j];
        s += __shfl_xor(s, 1); s += __shfl_xor(s, 2);
        s += __shfl_xor(s, 4); s += __shfl_xor(s, 8);
        if (cl == 0) atomicAdd(&red[r], s);
      }
    __syncthreads();
#pragma unroll
    for (int m = 0; m < 4; ++m)
#pragma unroll
      for (int j = 0; j < 4; ++j) {
        int r = wm * 64 + m * 16 + rj + j;
        float sc = 1.f / fmaxf(sqrtf(red[r]), 1e-12f);
#pragma unroll
        for (int n = 0; n < 8; ++n) {
          int col = wn * 128 + n * 16 + cl;
          p.out[(size_t)(row0 + r) * XROW + outofs + col] = acc[m][n][j] * sc;
        }
      }
  }
#undef STAGE
#undef CSTEP
}

// K4: attn_c = q.kc ; xc_ = attn_c*xc + sum ap*xp + sum an*xn ; xcn = bf16(l2norm(xc_))
__launch_bounds__(128)
__global__ void combine(Params p) {
  __shared__ float sbuf[2];
  __shared__ float swt[16];
  const int b = blockIdx.x;
  const int t = threadIdx.x;    // 128 threads, 4 cols each
  const float* xrow = p.x + (size_t)b * XROW;

  const ushort4 q4 = reinterpret_cast<const ushort4*>(p.qw + (size_t)b * D)[t];
  const ushort4 c4 = reinterpret_cast<const ushort4*>(p.kcw + (size_t)b * D)[t];
  float s = bf2f(q4.x) * bf2f(c4.x) + bf2f(q4.y) * bf2f(c4.y) +
            bf2f(q4.z) * bf2f(c4.z) + bf2f(q4.w) * bf2f(c4.w);
  for (int m = 32; m >= 1; m >>= 1) s += __shfl_xor(s, m);
  if ((t & 63) == 0) sbuf[t >> 6] = s;
  if (t < 8)       swt[t] = p.ap[(size_t)b * NW + t];
  else if (t < 16) swt[t] = p.an[(size_t)b * NW + (t - 8)];
  __syncthreads();
  const float att = sbuf[0] + sbuf[1];

  float4 xc4 = reinterpret_cast<const float4*>(xrow + 8 * D)[t];
  float4 v;
  v.x = xc4.x * att; v.y = xc4.y * att; v.z = xc4.z * att; v.w = xc4.w * att;
#pragma unroll
  for (int w = 0; w < 8; ++w) {
    float aw = swt[w], nw2 = swt[8 + w];
    float4 xp4 = reinterpret_cast<const float4*>(xrow + w * D)[t];
    float4 xn4 = reinterpret_cast<const float4*>(xrow + (9 + w) * D)[t];
    v.x += aw * xp4.x + nw2 * xn4.x;
    v.y += aw * xp4.y + nw2 * xn4.y;
    v.z += aw * xp4.z + nw2 * xn4.z;
    v.w += aw * xp4.w + nw2 * xn4.w;
  }
  float ss = v.x * v.x + v.y * v.y + v.z * v.z + v.w * v.w;
  __syncthreads();   // sbuf reuse guard
  for (int m = 32; m >= 1; m >>= 1) ss += __shfl_xor(ss, m);
  if ((t & 63) == 0) sbuf[t >> 6] = ss;
  __syncthreads();
  float sc = 1.f / fmaxf(sqrtf(sbuf[0] + sbuf[1]), 1e-12f);
  ushort4 o;
  o.x = f2bf(v.x * sc); o.y = f2bf(v.y * sc);
  o.z = f2bf(v.z * sc); o.w = f2bf(v.w * sc);
  reinterpret_cast<ushort4*>(p.xcn + (size_t)b * D)[t] = o;
}

extern "C" void kernel_launch(void* const* d_in, const int* in_sizes, int n_in,
                              void* d_out, int out_size, void* d_ws, size_t ws_size,
                              hipStream_t stream) {
  const float* x   = (const float*)d_in[0];
  const float* Wq  = (const float*)d_in[1];
  const float* bq  = (const float*)d_in[2];
  const float* Wkc = (const float*)d_in[3];
  const float* bkc = (const float*)d_in[4];
  const float* Wkp = (const float*)d_in[5];
  const float* bkp = (const float*)d_in[6];
  const float* Wkn = (const float*)d_in[7];
  const float* bkn = (const float*)d_in[8];
  const float* Wfp = (const float*)d_in[9];
  const float* bfp = (const float*)d_in[10];
  const float* Wfn = (const float*)d_in[11];
  const float* bfn = (const float*)d_in[12];
  const float* Wfc = (const float*)d_in[13];
  const float* bfc = (const float*)d_in[14];

  char* ws = (char*)d_ws;
  unsigned short* Wb  = (unsigned short*)ws;               // 18,350,080 B
  unsigned short* xb  = (unsigned short*)(ws + 18350080);  // 142,606,336 B
  unsigned short* qw  = (unsigned short*)(ws + 160956416); //   8,388,608 B
  unsigned short* kcw = (unsigned short*)(ws + 169345024); //   8,388,608 B
  float* ap  = (float*)(ws + 177733632);                   //     262,144 B
  float* an  = (float*)(ws + 177995776);                   //     262,144 B
  unsigned short* xcn = (unsigned short*)(ws + 178257920); //   8,388,608 B
  // total ws use: 186,646,528 B (~178 MB)

  Params p { x, bq, bkc, bkp, bkn, bfp, bfn, bfc, Wb, xb, qw, kcw, ap, an, xcn, (float*)d_out };

  hipLaunchKernelGGL(convert_all, dim3(4096), dim3(256), 0, stream,
                     x, Wq, Wkc, Wkp, Wkn, Wfp, Wfn, Wfc, Wb, xb);
  hipLaunchKernelGGL(gemm_mega, dim3(18 * 64), dim3(512), 0, stream, p, 0); // q,kc,fp,fn
  hipLaunchKernelGGL(gemm_mega, dim3(16 * 64), dim3(512), 0, stream, p, 1); // ap,an
  hipLaunchKernelGGL(combine,   dim3(8192),   dim3(128), 0, stream, p);     // xcn
  hipLaunchKernelGGL(gemm_mega, dim3(64),     dim3(512), 0, stream, p, 2);  // Wfc+resid
}

// Round 5
// 935.874 us; speedup vs baseline: 1.0108x; 1.0108x over previous
//
#include <hip/hip_runtime.h>
#include <stdint.h>

#define D 512
#define NW 8
#define BATCH 8192
#define XROW 8704          // 17*D
#define BM 128
#define BK 32
#define KT 16              // 512 / BK
#define MAT 262144         // 512*512

typedef __attribute__((ext_vector_type(8))) short bf16x8;
typedef __attribute__((ext_vector_type(4))) float f32x4;

struct Params {
  const float* x;
  const float* bq; const float* bkc;
  const float* bkp; const float* bkn;
  const float* bfp; const float* bfn;
  const float* bfc;
  const unsigned short* Wb;   // 35 bf16 512x512 matrices
  const unsigned short* xb;   // bf16 copy of x [B][17*D]
  unsigned short* qw;         // q  bf16 [B][D]
  unsigned short* kcw;        // kc bf16 [B][D]
  float* ap; float* an;       // [B][8]
  unsigned short* xcn;        // normalized center bf16 [B][D]
  float* out;
};

__device__ __forceinline__ unsigned short f2bf(float f) {
  union { float f; unsigned u; } v; v.f = f;
  unsigned u = v.u + 0x7FFFu + ((v.u >> 16) & 1u);   // RNE
  return (unsigned short)(u >> 16);
}
__device__ __forceinline__ float bf2f(unsigned short h) {
  union { unsigned u; float f; } v; v.u = ((unsigned)h) << 16;
  return v.f;
}

// K0: convert weights AND x fp32 -> bf16 into ws.
__global__ void convert_all(const float* x, const float* Wq, const float* Wkc,
                            const float* Wkp, const float* Wkn, const float* Wfp,
                            const float* Wfn, const float* Wfc,
                            unsigned short* Wb, unsigned short* xb) {
  const int totW = 35 * MAT;
  const int total4 = (totW + BATCH * XROW) / 4;
  for (int i4 = blockIdx.x * blockDim.x + threadIdx.x; i4 < total4;
       i4 += gridDim.x * blockDim.x) {
    int idx = i4 * 4;
    const float* src;
    unsigned short* dst;
    if (idx < totW) {
      int m = idx >> 18;
      int e = idx & (MAT - 1);
      if (m == 0)       src = Wq + e;
      else if (m == 1)  src = Wkc + e;
      else if (m < 10)  src = Wkp + (size_t)(m - 2) * MAT + e;
      else if (m < 18)  src = Wkn + (size_t)(m - 10) * MAT + e;
      else if (m < 26)  src = Wfp + (size_t)(m - 18) * MAT + e;
      else if (m < 34)  src = Wfn + (size_t)(m - 26) * MAT + e;
      else              src = Wfc + e;
      dst = Wb + idx;
    } else {
      int e = idx - totW;
      src = x + e;
      dst = xb + e;
    }
    float4 v = *reinterpret_cast<const float4*>(src);
    ushort4 o;
    o.x = f2bf(v.x); o.y = f2bf(v.y); o.z = f2bf(v.z); o.w = f2bf(v.w);
    *reinterpret_cast<ushort4*>(dst) = o;
  }
}

#define GLOAD(SRC, DST) __builtin_amdgcn_global_load_lds( \
    (const __attribute__((address_space(1))) unsigned*)(SRC), \
    (__attribute__((address_space(3))) unsigned*)(DST), 16, 0, 0)

// Pipelined batched GEMM, BM=128 x BN=512(full) x BK=32, 512 threads (8 waves,
// 2Mx4N, wave-tile 64x128). A and B staged bf16 via global_load_lds with
// rule-21 pre-swizzled source (involution o^((o>>3)&0x70) on 64-B rows).
// DEPTH-2 pipeline (R5): 3 LDS buffers (120 KB; occupancy is VGPR-capped at
// 1 block/CU anyway, so LDS is free), counted vmcnt(10) steady-state so each
// tile's loads get ~2 compute-phases (>800 cyc) to land. Tail 10->5->0.
// Barrier invariants identical to the R4 template that passed on HW.
__launch_bounds__(512)
__global__ void gemm_mega(Params p, int launch_id) {
  __shared__ unsigned short lds2[3][20480];  // 3 x (A 8KB @0 + B 32KB @4096e) = 120 KiB

  const int nchunk = gridDim.x >> 3;         // gridDim.x % 8 == 0 for all launches
  const int swz  = (blockIdx.x & 7) * nchunk + (blockIdx.x >> 3);
  const int unit = swz >> 6;
  const int mb   = swz & 63;
  const int t    = threadIdx.x;
  const int lane = t & 63;
  const int wave = t >> 6;
  const int wm   = wave >> 2;   // 0..1  (64 rows each)
  const int wn   = wave & 3;    // 0..3  (128 cols each)

  const unsigned short* Aab = p.xb;
  int lda = XROW;
  int aofs = 0;
  const unsigned short* Wm = p.Wb;
  const float* bias = p.bq;
  int epi = 0;
  int outofs = 0;
  float* dotdst = nullptr;
  int wofs = 0;

  if (launch_id == 0) {
    if (unit == 0)      { aofs = 8 * D; Wm = p.Wb;            bias = p.bq;  epi = 0; }
    else if (unit == 1) { aofs = 8 * D; Wm = p.Wb + MAT;      bias = p.bkc; epi = 1; }
    else if (unit < 10) { int w = unit - 2;  aofs = w * D;
                          Wm = p.Wb + (size_t)(18 + w) * MAT; bias = p.bfp + w * D;
                          epi = 2; outofs = w * D; }
    else                { int w = unit - 10; aofs = (9 + w) * D;
                          Wm = p.Wb + (size_t)(26 + w) * MAT; bias = p.bfn + w * D;
                          epi = 2; outofs = (9 + w) * D; }
  } else if (launch_id == 1) {
    if (unit < 8) { int w = unit;     aofs = w * D;
                    Wm = p.Wb + (size_t)(2 + w) * MAT;  bias = p.bkp + w * D;
                    epi = 3; dotdst = p.ap; wofs = w; }
    else          { int w = unit - 8; aofs = (9 + w) * D;
                    Wm = p.Wb + (size_t)(10 + w) * MAT; bias = p.bkn + w * D;
                    epi = 3; dotdst = p.an; wofs = w; }
  } else {
    Aab = p.xcn; lda = D; aofs = 0;
    Wm = p.Wb + (size_t)34 * MAT; bias = p.bfc; epi = 4; outofs = 8 * D;
  }

  const int row0 = mb * BM;

  f32x4 acc[4][8];
#pragma unroll
  for (int m = 0; m < 4; ++m)
#pragma unroll
    for (int n = 0; n < 8; ++n)
      acc[m][n] = (f32x4){0.f, 0.f, 0.f, 0.f};

  // Per-thread pre-swizzled global sources (kt=0); kt advances by +32 elems.
  const unsigned short* aST;
  {
    int o = t * 16; int Ls = o ^ ((o >> 3) & 0x70);
    aST = Aab + (size_t)(row0 + (Ls >> 6)) * lda + aofs + ((Ls & 63) >> 1);
  }
  const unsigned short* bSTa[4];
#pragma unroll
  for (int j = 0; j < 4; ++j) {
    int o = t * 16 + j * 8192; int Ls = o ^ ((o >> 3) & 0x70);
    bSTa[j] = Wm + (size_t)(Ls >> 6) * D + ((Ls & 63) >> 1);
  }

#define STAGE(S, KE) do { \
    GLOAD(aST + (KE), &lds2[S][0] + wave * 512); \
    _Pragma("unroll") \
    for (int j = 0; j < 4; ++j) \
      GLOAD(bSTa[j] + (KE), &lds2[S][4096 + j * 4096] + wave * 512); \
  } while (0)

#define CSTEP(S) do { \
    bf16x8 af[4], bfr[8]; \
    const int kb = (lane >> 4) * 16; \
    _Pragma("unroll") for (int m = 0; m < 4; ++m) { \
      int L = ((wm * 64 + m * 16 + (lane & 15)) << 6) + kb; \
      af[m] = *reinterpret_cast<const bf16x8*>((const char*)&lds2[S][0] + (L ^ ((L >> 3) & 0x70))); } \
    _Pragma("unroll") for (int n = 0; n < 8; ++n) { \
      int L = ((wn * 128 + n * 16 + (lane & 15)) << 6) + kb; \
      bfr[n] = *reinterpret_cast<const bf16x8*>((const char*)&lds2[S][4096] + (L ^ ((L >> 3) & 0x70))); } \
    asm volatile("s_waitcnt lgkmcnt(0)" ::: "memory"); \
    __builtin_amdgcn_sched_barrier(0); \
    __builtin_amdgcn_s_setprio(1); \
    _Pragma("unroll") for (int m = 0; m < 4; ++m) \
      _Pragma("unroll") for (int n = 0; n < 8; ++n) \
        acc[m][n] = __builtin_amdgcn_mfma_f32_16x16x32_bf16(af[m], bfr[n], acc[m][n], 0, 0, 0); \
    __builtin_amdgcn_s_setprio(0); \
  } while (0)

  STAGE(0, 0);
  STAGE(1, BK);
#pragma unroll
  for (int kt = 0; kt < KT - 2; ++kt) {
    STAGE((kt + 2) % 3, (kt + 2) * BK);
    __builtin_amdgcn_sched_barrier(0);
    asm volatile("s_waitcnt vmcnt(10)" ::: "memory");  // cur landed; 2 tiles in flight
    __builtin_amdgcn_sched_barrier(0);
    __builtin_amdgcn_s_barrier();
    __builtin_amdgcn_sched_barrier(0);
    CSTEP(kt % 3);
    __builtin_amdgcn_sched_barrier(0);
    __builtin_amdgcn_s_barrier();                      // readers done before buf rewritten next iter
  }
  // kt = KT-2: tile KT-1 still in flight
  __builtin_amdgcn_sched_barrier(0);
  asm volatile("s_waitcnt vmcnt(5)" ::: "memory");
  __builtin_amdgcn_sched_barrier(0);
  __builtin_amdgcn_s_barrier();
  __builtin_amdgcn_sched_barrier(0);
  CSTEP((KT - 2) % 3);
  __builtin_amdgcn_sched_barrier(0);
  __builtin_amdgcn_s_barrier();
  // kt = KT-1: final drain
  __builtin_amdgcn_sched_barrier(0);
  asm volatile("s_waitcnt vmcnt(0)" ::: "memory");
  __builtin_amdgcn_sched_barrier(0);
  __builtin_amdgcn_s_barrier();
  __builtin_amdgcn_sched_barrier(0);
  CSTEP((KT - 1) % 3);
  __builtin_amdgcn_sched_barrier(0);
  __builtin_amdgcn_s_barrier();

  // ---- epilogue (lds2[0] dead; overlay reduction buffer) ----
  float* red = (float*)(&lds2[0][0]);
  const int rj = (lane >> 4) * 4;
  const int cl = lane & 15;
  float bv[8];
#pragma unroll
  for (int n = 0; n < 8; ++n) bv[n] = bias[wn * 128 + n * 16 + cl];
#pragma unroll
  for (int m = 0; m < 4; ++m)
#pragma unroll
    for (int n = 0; n < 8; ++n)
#pragma unroll
      for (int j = 0; j < 4; ++j)
        acc[m][n][j] += bv[n];

  if (epi <= 1) {
    unsigned short* dst = (epi == 0) ? p.qw : p.kcw;
#pragma unroll
    for (int m = 0; m < 4; ++m)
#pragma unroll
      for (int j = 0; j < 4; ++j) {
        int r = wm * 64 + m * 16 + rj + j;
#pragma unroll
        for (int n = 0; n < 8; ++n) {
          int col = wn * 128 + n * 16 + cl;
          dst[(size_t)(row0 + r) * D + col] = f2bf(acc[m][n][j]);
        }
      }
  } else if (epi == 3) {
    if (t < BM) red[t] = 0.f;
    __syncthreads();
#pragma unroll
    for (int m = 0; m < 4; ++m)
#pragma unroll
      for (int j = 0; j < 4; ++j) {
        int r = wm * 64 + m * 16 + rj + j;
        float s = 0.f;
#pragma unroll
        for (int n = 0; n < 8; ++n) {
          int col = wn * 128 + n * 16 + cl;
          s += acc[m][n][j] * bf2f(p.qw[(size_t)(row0 + r) * D + col]);
        }
        s += __shfl_xor(s, 1); s += __shfl_xor(s, 2);
        s += __shfl_xor(s, 4); s += __shfl_xor(s, 8);
        if (cl == 0) atomicAdd(&red[r], s);
      }
    __syncthreads();
    if (t < BM) dotdst[(size_t)(row0 + t) * NW + wofs] = red[t];
  } else {
    if (epi == 4) {
#pragma unroll
      for (int m = 0; m < 4; ++m)
#pragma unroll
        for (int j = 0; j < 4; ++j) {
          int r = wm * 64 + m * 16 + rj + j;
#pragma unroll
          for (int n = 0; n < 8; ++n) {
            int col = wn * 128 + n * 16 + cl;
            acc[m][n][j] += p.x[(size_t)(row0 + r) * XROW + 8 * D + col];
          }
        }
    }
    if (t < BM) red[t] = 0.f;
    __syncthreads();
#pragma unroll
    for (int m = 0; m < 4; ++m)
#pragma unroll
      for (int j = 0; j < 4; ++j) {
        int r = wm * 64 + m * 16 + rj + j;
        float s = 0.f;
#pragma unroll
        for (int n = 0; n < 8; ++n) s += acc[m][n][j] * acc[m][n][j];
        s += __shfl_xor(s, 1); s += __shfl_xor(s, 2);
        s += __shfl_xor(s, 4); s += __shfl_xor(s, 8);
        if (cl == 0) atomicAdd(&red[r], s);
      }
    __syncthreads();
#pragma unroll
    for (int m = 0; m < 4; ++m)
#pragma unroll
      for (int j = 0; j < 4; ++j) {
        int r = wm * 64 + m * 16 + rj + j;
        float sc = 1.f / fmaxf(sqrtf(red[r]), 1e-12f);
#pragma unroll
        for (int n = 0; n < 8; ++n) {
          int col = wn * 128 + n * 16 + cl;
          p.out[(size_t)(row0 + r) * XROW + outofs + col] = acc[m][n][j] * sc;
        }
      }
  }
#undef STAGE
#undef CSTEP
}

// K4: attn_c = q.kc ; xc_ = attn_c*xc + sum ap*xp + sum an*xn ; xcn = bf16(l2norm(xc_))
__launch_bounds__(128)
__global__ void combine(Params p) {
  __shared__ float sbuf[2];
  __shared__ float swt[16];
  const int b = blockIdx.x;
  const int t = threadIdx.x;    // 128 threads, 4 cols each
  const float* xrow = p.x + (size_t)b * XROW;

  const ushort4 q4 = reinterpret_cast<const ushort4*>(p.qw + (size_t)b * D)[t];
  const ushort4 c4 = reinterpret_cast<const ushort4*>(p.kcw + (size_t)b * D)[t];
  float s = bf2f(q4.x) * bf2f(c4.x) + bf2f(q4.y) * bf2f(c4.y) +
            bf2f(q4.z) * bf2f(c4.z) + bf2f(q4.w) * bf2f(c4.w);
  for (int m = 32; m >= 1; m >>= 1) s += __shfl_xor(s, m);
  if ((t & 63) == 0) sbuf[t >> 6] = s;
  if (t < 8)       swt[t] = p.ap[(size_t)b * NW + t];
  else if (t < 16) swt[t] = p.an[(size_t)b * NW + (t - 8)];
  __syncthreads();
  const float att = sbuf[0] + sbuf[1];

  float4 xc4 = reinterpret_cast<const float4*>(xrow + 8 * D)[t];
  float4 v;
  v.x = xc4.x * att; v.y = xc4.y * att; v.z = xc4.z * att; v.w = xc4.w * att;
#pragma unroll
  for (int w = 0; w < 8; ++w) {
    float aw = swt[w], nw2 = swt[8 + w];
    float4 xp4 = reinterpret_cast<const float4*>(xrow + w * D)[t];
    float4 xn4 = reinterpret_cast<const float4*>(xrow + (9 + w) * D)[t];
    v.x += aw * xp4.x + nw2 * xn4.x;
    v.y += aw * xp4.y + nw2 * xn4.y;
    v.z += aw * xp4.z + nw2 * xn4.z;
    v.w += aw * xp4.w + nw2 * xn4.w;
  }
  float ss = v.x * v.x + v.y * v.y + v.z * v.z + v.w * v.w;
  __syncthreads();   // sbuf reuse guard
  for (int m = 32; m >= 1; m >>= 1) ss += __shfl_xor(ss, m);
  if ((t & 63) == 0) sbuf[t >> 6] = ss;
  __syncthreads();
  float sc = 1.f / fmaxf(sqrtf(sbuf[0] + sbuf[1]), 1e-12f);
  ushort4 o;
  o.x = f2bf(v.x * sc); o.y = f2bf(v.y * sc);
  o.z = f2bf(v.z * sc); o.w = f2bf(v.w * sc);
  reinterpret_cast<ushort4*>(p.xcn + (size_t)b * D)[t] = o;
}

extern "C" void kernel_launch(void* const* d_in, const int* in_sizes, int n_in,
                              void* d_out, int out_size, void* d_ws, size_t ws_size,
                              hipStream_t stream) {
  const float* x   = (const float*)d_in[0];
  const float* Wq  = (const float*)d_in[1];
  const float* bq  = (const float*)d_in[2];
  const float* Wkc = (const float*)d_in[3];
  const float* bkc = (const float*)d_in[4];
  const float* Wkp = (const float*)d_in[5];
  const float* bkp = (const float*)d_in[6];
  const float* Wkn = (const float*)d_in[7];
  const float* bkn = (const float*)d_in[8];
  const float* Wfp = (const float*)d_in[9];
  const float* bfp = (const float*)d_in[10];
  const float* Wfn = (const float*)d_in[11];
  const float* bfn = (const float*)d_in[12];
  const float* Wfc = (const float*)d_in[13];
  const float* bfc = (const float*)d_in[14];

  char* ws = (char*)d_ws;
  unsigned short* Wb  = (unsigned short*)ws;               // 18,350,080 B
  unsigned short* xb  = (unsigned short*)(ws + 18350080);  // 142,606,336 B
  unsigned short* qw  = (unsigned short*)(ws + 160956416); //   8,388,608 B
  unsigned short* kcw = (unsigned short*)(ws + 169345024); //   8,388,608 B
  float* ap  = (float*)(ws + 177733632);                   //     262,144 B
  float* an  = (float*)(ws + 177995776);                   //     262,144 B
  unsigned short* xcn = (unsigned short*)(ws + 178257920); //   8,388,608 B
  // total ws use: 186,646,528 B (~178 MB)

  Params p { x, bq, bkc, bkp, bkn, bfp, bfn, bfc, Wb, xb, qw, kcw, ap, an, xcn, (float*)d_out };

  hipLaunchKernelGGL(convert_all, dim3(4096), dim3(256), 0, stream,
                     x, Wq, Wkc, Wkp, Wkn, Wfp, Wfn, Wfc, Wb, xb);
  hipLaunchKernelGGL(gemm_mega, dim3(18 * 64), dim3(512), 0, stream, p, 0); // q,kc,fp,fn
  hipLaunchKernelGGL(gemm_mega, dim3(16 * 64), dim3(512), 0, stream, p, 1); // ap,an
  hipLaunchKernelGGL(combine,   dim3(8192),   dim3(128), 0, stream, p);     // xcn
  hipLaunchKernelGGL(gemm_mega, dim3(64),     dim3(512), 0, stream, p, 2);  // Wfc+resid
}

// Round 7
// 831.672 us; speedup vs baseline: 1.1374x; 1.1253x over previous
//
#include <hip/hip_runtime.h>
#include <stdint.h>

#define D 512
#define NW 8
#define BATCH 8192
#define XROW 8704          // 17*D
#define BM 128
#define BK 32
#define KT 16              // 512 / BK
#define MAT 262144         // 512*512
#define BUFB 40960         // bytes per LDS pipeline buffer: A 8KB + B 32KB

typedef __attribute__((ext_vector_type(8))) short bf16x8;
typedef __attribute__((ext_vector_type(4))) float f32x4;

struct Params {
  const float* x;
  const float* bq; const float* bkc;
  const float* bkp; const float* bkn;
  const float* bfp; const float* bfn;
  const float* bfc;
  const unsigned short* Wb;   // 35 bf16 512x512 matrices
  unsigned short* qw;         // q  bf16 [B][D]
  unsigned short* kcw;        // kc bf16 [B][D]
  float* ap; float* an;       // [B][8]
  float* xcn;                 // normalized center fp32 [B][D]
  float* out;
};

__device__ __forceinline__ unsigned short f2bf(float f) {
  union { float f; unsigned u; } v; v.f = f;
  unsigned u = v.u + 0x7FFFu + ((v.u >> 16) & 1u);   // RNE
  return (unsigned short)(u >> 16);
}
__device__ __forceinline__ float bf2f(unsigned short h) {
  union { unsigned u; float f; } v; v.u = ((unsigned)h) << 16;
  return v.f;
}

// K0: convert weight matrices only, fp32 -> bf16 (order:
// Wq, Wkc, Wkp[0..7], Wkn[0..7], Wfp[0..7], Wfn[0..7], Wfc). ~110 MB traffic.
__global__ void convert_weights(const float* Wq, const float* Wkc, const float* Wkp,
                                const float* Wkn, const float* Wfp, const float* Wfn,
                                const float* Wfc, unsigned short* outw) {
  const int total4 = 35 * MAT / 4;
  for (int i4 = blockIdx.x * blockDim.x + threadIdx.x; i4 < total4;
       i4 += gridDim.x * blockDim.x) {
    int idx = i4 * 4;
    int m = idx >> 18;
    int e = idx & (MAT - 1);
    const float* src;
    if (m == 0)       src = Wq + e;
    else if (m == 1)  src = Wkc + e;
    else if (m < 10)  src = Wkp + (size_t)(m - 2) * MAT + e;
    else if (m < 18)  src = Wkn + (size_t)(m - 10) * MAT + e;
    else if (m < 26)  src = Wfp + (size_t)(m - 18) * MAT + e;
    else if (m < 34)  src = Wfn + (size_t)(m - 26) * MAT + e;
    else              src = Wfc + e;
    float4 v = *reinterpret_cast<const float4*>(src);
    ushort4 o;
    o.x = f2bf(v.x); o.y = f2bf(v.y); o.z = f2bf(v.z); o.w = f2bf(v.w);
    *reinterpret_cast<ushort4*>(outw + idx) = o;
  }
}

#define GLOAD(SRC, DST) __builtin_amdgcn_global_load_lds( \
    (const __attribute__((address_space(1))) unsigned*)(SRC), \
    (__attribute__((address_space(3))) unsigned*)(DST), 16, 0, 0)

// Pipelined batched GEMM, BM=128 x BN=512(full) x BK=32, 512 threads (8 waves,
// 2Mx4N, wave-tile 64x128). A staged fp32->bf16 in-kernel (reg-prefetch 1 iter,
// convert+swizzled ds_write); B staged via global_load_lds w/ rule-21
// pre-swizzled source. ONE barrier per kt: staging writes are drained by the
// CSTEP-internal lgkmcnt(0) + counted vmcnt before the barrier. Rolled loop
// (unroll 2 for static buffer parity) to keep the hot code I-cache-resident.
__launch_bounds__(512)
__global__ void gemm_mega(Params p, int launch_id) {
  __shared__ unsigned short lds2[2][BUFB / 2];  // 80 KiB total

  const int nchunk = gridDim.x >> 3;         // gridDim.x % 8 == 0 for all launches
  const int swz  = (blockIdx.x & 7) * nchunk + (blockIdx.x >> 3);
  const int unit = swz >> 6;
  const int mb   = swz & 63;
  const int t    = threadIdx.x;
  const int lane = t & 63;
  const int wave = t >> 6;
  const int wm   = wave >> 2;   // 0..1  (64 rows each)
  const int wn   = wave & 3;    // 0..3  (128 cols each)

  const float* Aptr = p.x;
  int lda = XROW;
  int aofs = 0;
  const unsigned short* Wm = p.Wb;
  const float* bias = p.bq;
  int epi = 0;
  int outofs = 0;
  float* dotdst = nullptr;
  int wofs = 0;

  if (launch_id == 0) {
    if (unit == 0)      { aofs = 8 * D; Wm = p.Wb;            bias = p.bq;  epi = 0; }
    else if (unit == 1) { aofs = 8 * D; Wm = p.Wb + MAT;      bias = p.bkc; epi = 1; }
    else if (unit < 10) { int w = unit - 2;  aofs = w * D;
                          Wm = p.Wb + (size_t)(18 + w) * MAT; bias = p.bfp + w * D;
                          epi = 2; outofs = w * D; }
    else                { int w = unit - 10; aofs = (9 + w) * D;
                          Wm = p.Wb + (size_t)(26 + w) * MAT; bias = p.bfn + w * D;
                          epi = 2; outofs = (9 + w) * D; }
  } else if (launch_id == 1) {
    if (unit < 8) { int w = unit;     aofs = w * D;
                    Wm = p.Wb + (size_t)(2 + w) * MAT;  bias = p.bkp + w * D;
                    epi = 3; dotdst = p.ap; wofs = w; }
    else          { int w = unit - 8; aofs = (9 + w) * D;
                    Wm = p.Wb + (size_t)(10 + w) * MAT; bias = p.bkn + w * D;
                    epi = 3; dotdst = p.an; wofs = w; }
  } else {
    Aptr = p.xcn; lda = D; aofs = 0;
    Wm = p.Wb + (size_t)34 * MAT; bias = p.bfc; epi = 4; outofs = 8 * D;
  }

  const int row0 = mb * BM;

  f32x4 acc[4][8];
#pragma unroll
  for (int m = 0; m < 4; ++m)
#pragma unroll
    for (int n = 0; n < 8; ++n)
      acc[m][n] = (f32x4){0.f, 0.f, 0.f, 0.f};

  char* lbase = (char*)lds2;

  // ---- A staging map: thread -> (row ar, 8-float chunk) ----
  const int ar  = t >> 2;              // 0..127
  const int akb = (t & 3) * 16;        // byte offset of chunk within 64-B LDS row
  const float* a_src = Aptr + (size_t)(row0 + ar) * lda + aofs + (t & 3) * 8;

  // ---- B staging: pre-swizzled global sources (rule 21 involution) ----
  const unsigned short* bSTa[4];
#pragma unroll
  for (int j = 0; j < 4; ++j) {
    int o = j * 8192 + t * 16;                 // linear byte offset in B region
    int Ls = o ^ ((o >> 3) & 0x70);            // involution: bits4-6 ^= bits7-9
    bSTa[j] = Wm + (size_t)(Ls >> 6) * D + ((Ls & 63) >> 1);
  }

  // ---- precomputed swizzled ds_read offsets ----
  const int kb = (lane >> 4) * 16;
  int aoff[4], boff[8];
#pragma unroll
  for (int m = 0; m < 4; ++m) {
    int L = ((wm * 64 + m * 16 + (lane & 15)) << 6) + kb;
    aoff[m] = L ^ ((L >> 3) & 0x70);
  }
#pragma unroll
  for (int n = 0; n < 8; ++n) {
    int L = ((wn * 128 + n * 16 + (lane & 15)) << 6) + kb;
    boff[n] = 8192 + (L ^ ((L >> 3) & 0x70));
  }

#define STAGE_B(S, KE) do { \
    _Pragma("unroll") \
    for (int j = 0; j < 4; ++j) \
      GLOAD(bSTa[j] + (KE), lbase + (S) * BUFB + 8192 + j * 8192 + t * 16); \
  } while (0)

#define CVTWR(S, A0, A1) do { \
    bf16x8 pk; \
    pk[0] = (short)f2bf((A0).x); pk[1] = (short)f2bf((A0).y); \
    pk[2] = (short)f2bf((A0).z); pk[3] = (short)f2bf((A0).w); \
    pk[4] = (short)f2bf((A1).x); pk[5] = (short)f2bf((A1).y); \
    pk[6] = (short)f2bf((A1).z); pk[7] = (short)f2bf((A1).w); \
    int bo = (ar << 6) + akb; \
    *reinterpret_cast<bf16x8*>(lbase + (S) * BUFB + (bo ^ ((bo >> 3) & 0x70))) = pk; \
  } while (0)

#define CSTEP(S) do { \
    bf16x8 af[4], bfr[8]; \
    _Pragma("unroll") for (int m = 0; m < 4; ++m) \
      af[m] = *reinterpret_cast<const bf16x8*>(lbase + (S) * BUFB + aoff[m]); \
    _Pragma("unroll") for (int n = 0; n < 8; ++n) \
      bfr[n] = *reinterpret_cast<const bf16x8*>(lbase + (S) * BUFB + boff[n]); \
    asm volatile("s_waitcnt lgkmcnt(0)" ::: "memory"); \
    __builtin_amdgcn_sched_barrier(0); \
    __builtin_amdgcn_s_setprio(1); \
    _Pragma("unroll") for (int m = 0; m < 4; ++m) \
      _Pragma("unroll") for (int n = 0; n < 8; ++n) \
        acc[m][n] = __builtin_amdgcn_mfma_f32_16x16x32_bf16(af[m], bfr[n], acc[m][n], 0, 0, 0); \
    __builtin_amdgcn_s_setprio(0); \
  } while (0)

  // ---- prologue: fill buf0, prefetch A(1) regs ----
  float4 a0 = *reinterpret_cast<const float4*>(a_src);
  float4 a1 = *reinterpret_cast<const float4*>(a_src + 4);
  STAGE_B(0, 0);
  CVTWR(0, a0, a1);                                    // implicit vmcnt(4): A(0) regs ready
  a0 = *reinterpret_cast<const float4*>(a_src + BK);
  a1 = *reinterpret_cast<const float4*>(a_src + BK + 4);
  asm volatile("s_waitcnt vmcnt(2)" ::: "memory");     // B(0) landed; A(1) in flight
  asm volatile("s_waitcnt lgkmcnt(0)" ::: "memory");   // A(0) ds_write drained
  __builtin_amdgcn_sched_barrier(0);
  __builtin_amdgcn_s_barrier();

#pragma unroll 2
  for (int kt = 0; kt < KT; ++kt) {
    const int cur = kt & 1;
    if (kt < KT - 1) {
      STAGE_B(cur ^ 1, (kt + 1) * BK);
      CVTWR(cur ^ 1, a0, a1);                          // implicit vmcnt(4): A(kt+1) regs ready
      if (kt < KT - 2) {
        a0 = *reinterpret_cast<const float4*>(a_src + (kt + 2) * BK);
        a1 = *reinterpret_cast<const float4*>(a_src + (kt + 2) * BK + 4);
      }
    }
    CSTEP(cur);                                        // contains lgkmcnt(0) drain
    if (kt < KT - 2)
      asm volatile("s_waitcnt vmcnt(2)" ::: "memory"); // B(kt+1) landed; A(kt+2) in flight
    else if (kt == KT - 2)
      asm volatile("s_waitcnt vmcnt(0)" ::: "memory"); // B(KT-1) landed (no A in flight)
    __builtin_amdgcn_sched_barrier(0);
    __builtin_amdgcn_s_barrier();
  }

  // ---- epilogue (LDS buffers dead; overlay reduction buffer) ----
  float* red = (float*)lbase;
  const int rj = (lane >> 4) * 4;
  const int cl = lane & 15;
  float bv[8];
#pragma unroll
  for (int n = 0; n < 8; ++n) bv[n] = bias[wn * 128 + n * 16 + cl];
#pragma unroll
  for (int m = 0; m < 4; ++m)
#pragma unroll
    for (int n = 0; n < 8; ++n)
#pragma unroll
      for (int j = 0; j < 4; ++j)
        acc[m][n][j] += bv[n];

  if (epi <= 1) {
    unsigned short* dst = (epi == 0) ? p.qw : p.kcw;
#pragma unroll
    for (int m = 0; m < 4; ++m)
#pragma unroll
      for (int j = 0; j < 4; ++j) {
        int r = wm * 64 + m * 16 + rj + j;
#pragma unroll
        for (int n = 0; n < 8; ++n) {
          int col = wn * 128 + n * 16 + cl;
          dst[(size_t)(row0 + r) * D + col] = f2bf(acc[m][n][j]);
        }
      }
  } else if (epi == 3) {
    if (t < BM) red[t] = 0.f;
    __syncthreads();
#pragma unroll
    for (int m = 0; m < 4; ++m)
#pragma unroll
      for (int j = 0; j < 4; ++j) {
        int r = wm * 64 + m * 16 + rj + j;
        float s = 0.f;
#pragma unroll
        for (int n = 0; n < 8; ++n) {
          int col = wn * 128 + n * 16 + cl;
          s += acc[m][n][j] * bf2f(p.qw[(size_t)(row0 + r) * D + col]);
        }
        s += __shfl_xor(s, 1); s += __shfl_xor(s, 2);
        s += __shfl_xor(s, 4); s += __shfl_xor(s, 8);
        if (cl == 0) atomicAdd(&red[r], s);
      }
    __syncthreads();
    if (t < BM) dotdst[(size_t)(row0 + t) * NW + wofs] = red[t];
  } else {
    if (epi == 4) {
#pragma unroll
      for (int m = 0; m < 4; ++m)
#pragma unroll
        for (int j = 0; j < 4; ++j) {
          int r = wm * 64 + m * 16 + rj + j;
#pragma unroll
          for (int n = 0; n < 8; ++n) {
            int col = wn * 128 + n * 16 + cl;
            acc[m][n][j] += p.x[(size_t)(row0 + r) * XROW + 8 * D + col];
          }
        }
    }
    if (t < BM) red[t] = 0.f;
    __syncthreads();
#pragma unroll
    for (int m = 0; m < 4; ++m)
#pragma unroll
      for (int j = 0; j < 4; ++j) {
        int r = wm * 64 + m * 16 + rj + j;
        float s = 0.f;
#pragma unroll
        for (int n = 0; n < 8; ++n) s += acc[m][n][j] * acc[m][n][j];
        s += __shfl_xor(s, 1); s += __shfl_xor(s, 2);
        s += __shfl_xor(s, 4); s += __shfl_xor(s, 8);
        if (cl == 0) atomicAdd(&red[r], s);
      }
    __syncthreads();
#pragma unroll
    for (int m = 0; m < 4; ++m)
#pragma unroll
      for (int j = 0; j < 4; ++j) {
        int r = wm * 64 + m * 16 + rj + j;
        float sc = 1.f / fmaxf(sqrtf(red[r]), 1e-12f);
#pragma unroll
        for (int n = 0; n < 8; ++n) {
          int col = wn * 128 + n * 16 + cl;
          p.out[(size_t)(row0 + r) * XROW + outofs + col] = acc[m][n][j] * sc;
        }
      }
  }
#undef STAGE_B
#undef CVTWR
#undef CSTEP
}

// K4: attn_c = q.kc ; xc_ = attn_c*xc + sum ap*xp + sum an*xn ; xcn = l2norm(xc_)
__launch_bounds__(128)
__global__ void combine(Params p) {
  __shared__ float sbuf[2];
  __shared__ float swt[16];
  const int b = blockIdx.x;
  const int t = threadIdx.x;    // 128 threads, 4 cols each
  const float* xrow = p.x + (size_t)b * XROW;

  const ushort4 q4 = reinterpret_cast<const ushort4*>(p.qw + (size_t)b * D)[t];
  const ushort4 c4 = reinterpret_cast<const ushort4*>(p.kcw + (size_t)b * D)[t];
  float s = bf2f(q4.x) * bf2f(c4.x) + bf2f(q4.y) * bf2f(c4.y) +
            bf2f(q4.z) * bf2f(c4.z) + bf2f(q4.w) * bf2f(c4.w);
  for (int m = 32; m >= 1; m >>= 1) s += __shfl_xor(s, m);
  if ((t & 63) == 0) sbuf[t >> 6] = s;
  if (t < 8)       swt[t] = p.ap[(size_t)b * NW + t];
  else if (t < 16) swt[t] = p.an[(size_t)b * NW + (t - 8)];
  __syncthreads();
  const float att = sbuf[0] + sbuf[1];

  float4 xc4 = reinterpret_cast<const float4*>(xrow + 8 * D)[t];
  float4 v;
  v.x = xc4.x * att; v.y = xc4.y * att; v.z = xc4.z * att; v.w = xc4.w * att;
#pragma unroll
  for (int w = 0; w < 8; ++w) {
    float aw = swt[w], nw2 = swt[8 + w];
    float4 xp4 = reinterpret_cast<const float4*>(xrow + w * D)[t];
    float4 xn4 = reinterpret_cast<const float4*>(xrow + (9 + w) * D)[t];
    v.x += aw * xp4.x + nw2 * xn4.x;
    v.y += aw * xp4.y + nw2 * xn4.y;
    v.z += aw * xp4.z + nw2 * xn4.z;
    v.w += aw * xp4.w + nw2 * xn4.w;
  }
  float ss = v.x * v.x + v.y * v.y + v.z * v.z + v.w * v.w;
  __syncthreads();   // sbuf reuse guard
  for (int m = 32; m >= 1; m >>= 1) ss += __shfl_xor(ss, m);
  if ((t & 63) == 0) sbuf[t >> 6] = ss;
  __syncthreads();
  float sc = 1.f / fmaxf(sqrtf(sbuf[0] + sbuf[1]), 1e-12f);
  float4 o; o.x = v.x * sc; o.y = v.y * sc; o.z = v.z * sc; o.w = v.w * sc;
  reinterpret_cast<float4*>(p.xcn + (size_t)b * D)[t] = o;
}

extern "C" void kernel_launch(void* const* d_in, const int* in_sizes, int n_in,
                              void* d_out, int out_size, void* d_ws, size_t ws_size,
                              hipStream_t stream) {
  const float* x   = (const float*)d_in[0];
  const float* Wq  = (const float*)d_in[1];
  const float* bq  = (const float*)d_in[2];
  const float* Wkc = (const float*)d_in[3];
  const float* bkc = (const float*)d_in[4];
  const float* Wkp = (const float*)d_in[5];
  const float* bkp = (const float*)d_in[6];
  const float* Wkn = (const float*)d_in[7];
  const float* bkn = (const float*)d_in[8];
  const float* Wfp = (const float*)d_in[9];
  const float* bfp = (const float*)d_in[10];
  const float* Wfn = (const float*)d_in[11];
  const float* bfn = (const float*)d_in[12];
  const float* Wfc = (const float*)d_in[13];
  const float* bfc = (const float*)d_in[14];

  char* ws = (char*)d_ws;
  unsigned short* Wb  = (unsigned short*)ws;              // 18,350,080 B
  unsigned short* qw  = (unsigned short*)(ws + 18350080); //  8,388,608 B
  unsigned short* kcw = (unsigned short*)(ws + 26738688); //  8,388,608 B
  float* ap  = (float*)(ws + 35127296);                   //    262,144 B
  float* an  = (float*)(ws + 35389440);                   //    262,144 B
  float* xcn = (float*)(ws + 35651584);                   // 16,777,216 B
  // total ws use: 52,428,800 B (50 MB)

  Params p { x, bq, bkc, bkp, bkn, bfp, bfn, bfc, Wb, qw, kcw, ap, an, xcn, (float*)d_out };

  hipLaunchKernelGGL(convert_weights, dim3(2048), dim3(256), 0, stream,
                     Wq, Wkc, Wkp, Wkn, Wfp, Wfn, Wfc, Wb);
  hipLaunchKernelGGL(gemm_mega, dim3(18 * 64), dim3(512), 0, stream, p, 0); // q,kc,fp,fn
  hipLaunchKernelGGL(gemm_mega, dim3(16 * 64), dim3(512), 0, stream, p, 1); // ap,an
  hipLaunchKernelGGL(combine,   dim3(8192),   dim3(128), 0, stream, p);     // xcn
  hipLaunchKernelGGL(gemm_mega, dim3(64),     dim3(512), 0, stream, p, 2);  // Wfc+resid
}